// Round 5
// baseline (740.497 us; speedup 1.0000x reference)
//
#include <hip/hip_runtime.h>
#include <hip/hip_bf16.h>
#include <math.h>

#define EPSF 1e-8f
#define LR   1e-3f

#define HH 512
#define KK 64
#define SS 4          // samples per block
#define PbStr 56      // Pb row stride (ush): 48 data + 8 pad (112B, 16B-mult)
#define GbStr 136     // Gb col stride (ush): 128 K + 8 pad (272B, 16B-mult)
#define SLICE 2176    // per-wave slice (ush) = 4352 B (= Gb 16*136; >= Pb 1792, dump 2048)

typedef short    bf16x8 __attribute__((ext_vector_type(8)));
typedef _Float16 f16x8  __attribute__((ext_vector_type(8)));
typedef _Float16 f16x4  __attribute__((ext_vector_type(4)));
typedef float    f32x4  __attribute__((ext_vector_type(4)));

__device__ __forceinline__ unsigned short f2bf(float x) {
  unsigned int u = __float_as_uint(x);
  return (unsigned short)((u + 0x7fffu + ((u >> 16) & 1u)) >> 16);
}
__device__ __forceinline__ float bfhi(float x) {
  return __uint_as_float(((unsigned int)f2bf(x)) << 16);
}
__device__ __forceinline__ unsigned short f2h(float x) {
  _Float16 h = (_Float16)x;
  return *(unsigned short*)&h;
}
__device__ __forceinline__ unsigned int pkbf2(float a, float b) {
  union { __hip_bfloat162 h; unsigned int u; } cv;
  cv.h = __float22bfloat162_rn(make_float2(a, b));
  return cv.u;
}

// ws layout (ushort units):
//  AFb @ 0      (131072): bwd A-frags, single bf16
//     f = ((chunk*4+qtr)*4+ks2)*4+mt; elem = f*512 + lane*8 + j
//     khat=mt*16+(lane&15); kq=(lane>>4)*8+j; h=chunk*128+qtr*32+kq; val=Ms[ks2][h*64+khat]
//  AFf @ 131072 (131072): fwd A-frags fp16
//     f=(z*32+ht)*2+kap; elem=f*512+lane*8+j
//     h=ht*16+(lane&15); kk=kap*32+(lane>>4)*8+j; val=Ms[z][h*64+kk]
//  AFp @ 262144 (65536): C0 A-frags bf16 hi/lo (Bp)
//     f=(ks*4+mt)*2+hilo; elem=f*512+lane*8+j
//     khat=mt*16+(lane&15); Kl=ks*32+(lane>>4)*8+j; val=Bp[khat*512+Kl]
__global__ void prep_kernel(const float* __restrict__ B,
                            const float* __restrict__ Bd,
                            const float* __restrict__ Bdd,
                            const float* __restrict__ Bddd,
                            const float* __restrict__ Bp,
                            unsigned short* __restrict__ ws) {
  int tid = blockIdx.x * 256 + threadIdx.x;   // 640 * 256 = 163840
  const float* Ms[4] = {B, Bd, Bdd, Bddd};
  unsigned short bits[2];
  if (tid < 65536) {
    #pragma unroll
    for (int t = 0; t < 2; ++t) {
      unsigned int id = 2u * tid + t;
      int j = id & 7, lane = (id >> 3) & 63;
      int mt = (id >> 9) & 3, ks2 = (id >> 11) & 3;
      int qtr = (id >> 13) & 3, chunk = (id >> 15) & 3;
      int khat = mt * 16 + (lane & 15);
      int kq = ((lane >> 4) << 3) + j;
      int h = chunk * 128 + qtr * 32 + kq;
      bits[t] = f2bf(Ms[ks2][h * 64 + khat]);
    }
    ((unsigned int*)ws)[tid] = ((unsigned int)bits[1] << 16) | bits[0];
  } else if (tid < 131072) {
    int base = tid - 65536;
    #pragma unroll
    for (int t = 0; t < 2; ++t) {
      unsigned int id = 2u * base + t;
      int j = id & 7, lane = (id >> 3) & 63, kap = (id >> 9) & 1;
      int ht = (id >> 10) & 31, z = (id >> 15) & 3;
      int h = ht * 16 + (lane & 15);
      int kk = kap * 32 + ((lane >> 4) << 3) + j;
      bits[t] = f2h(Ms[z][h * 64 + kk]);
    }
    ((unsigned int*)(ws + 131072))[base] = ((unsigned int)bits[1] << 16) | bits[0];
  } else {
    int base = tid - 131072;
    #pragma unroll
    for (int t = 0; t < 2; ++t) {
      unsigned int id = 2u * base + t;
      int j = id & 7, lane = (id >> 3) & 63, hilo = (id >> 9) & 1;
      int mt = (id >> 10) & 3, ks = (id >> 12) & 15;
      int khat = mt * 16 + (lane & 15);
      int Kl = ks * 32 + ((lane >> 4) << 3) + j;
      float val = Bp[khat * 512 + Kl];
      float hi = bfhi(val);
      bits[t] = hilo ? f2bf(val - hi) : f2bf(hi);
    }
    ((unsigned int*)(ws + 262144))[base] = ((unsigned int)bits[1] << 16) | bits[0];
  }
}

__global__ __launch_bounds__(256, 7)
void copt_kernel(const float* __restrict__ R_U,
                 const float* __restrict__ alpha,
                 const float* __restrict__ beta,
                 const float* __restrict__ lambdas,
                 const unsigned short* __restrict__ ws,
                 float* __restrict__ out) {
  __shared__ __align__(16) float Cl[SS][KK][3];            // 3 KB fp32 C
  __shared__ __align__(16) unsigned short Cbf[2 * 512];    // 2 KB fp16 C B-frags
  __shared__ __align__(16) unsigned short pool[4 * SLICE]; // 17 KB: per-wave Pb/Gb (aliased) + dump

  const unsigned short* AFb = ws;
  const unsigned short* AFf = ws + 131072;
  const unsigned short* AFp = ws + 262144;

  const int tid  = threadIdx.x;
  const int lane = tid & 63;
  const int wid  = tid >> 6;
  const int quad = lane >> 4;
  const int c    = lane & 15;

  const float l1 = lambdas[0], l2 = lambdas[1], l3 = lambdas[2];
  const int bg = blockIdx.x * SS;

  if (tid < 512) ((unsigned int*)Cbf)[tid] = 0u;   // cols 12..15 stay 0 forever

  // ---- stage r -> pool (bf16): [col=3s+m][h], stride 520 (s=wid) ----
  {
    const int s = wid, sg = bg + s;
    const float4* rp = (const float4*)(R_U + (size_t)sg * (HH * 3));
    #pragma unroll
    for (int i = 0; i < 6; ++i) {
      float4 v = rp[i * 64 + lane];
      int e = (i * 64 + lane) * 4;
      const float* pv = &v.x;
      #pragma unroll
      for (int d = 0; d < 4; ++d) {
        int ee = e + d, h = ee / 3, m = ee - 3 * h;
        pool[(3 * s + m) * 520 + h] = f2bf(pv[d]);
      }
    }
  }
  __syncthreads();

  // ---- C0 = Bp @ r via MFMA (bf16 hi/lo A, bf16 r); this wave: mt = wid ----
  {
    f32x4 cacc = {0.f, 0.f, 0.f, 0.f};
    const unsigned short* gb = &pool[c * 520 + quad * 8];
    #pragma unroll 4
    for (int ks = 0; ks < 16; ++ks) {
      const unsigned short* pA = AFp + (size_t)((ks * 4 + wid) * 2) * 512 + lane * 8;
      bf16x8 ah = *(const bf16x8*)pA;
      bf16x8 al = *(const bf16x8*)(pA + 512);
      bf16x8 gg = *(const bf16x8*)(gb + ks * 32);
      cacc = __builtin_amdgcn_mfma_f32_16x16x32_bf16(ah, gg, cacc, 0, 0, 0);
      cacc = __builtin_amdgcn_mfma_f32_16x16x32_bf16(al, gg, cacc, 0, 0, 0);
    }
    if (c < 12) {
      const int s = (c * 86) >> 8, m = c - 3 * s;
      const int kr = wid * 16 + quad * 4;
      #pragma unroll
      for (int r = 0; r < 4; ++r) {
        float val = cacc[r];
        int k = kr + r;
        Cl[s][k][m] = val;
        Cbf[(k >> 5) * 512 + (((k >> 3) & 3) * 16 + c) * 8 + (k & 7)] = f2h(val);
      }
    }
  }
  __syncthreads();

  // elem thread ids: h = hq (lane&31), sample-pair by lane>>5
  const int hq = lane & 31;
  const int es0 = 2 * (lane >> 5), es1 = es0 + 1;
  const float ea0 = alpha[bg + es0], ea1 = alpha[bg + es1];
  const float eb0 = beta[bg + es0],  eb1 = beta[bg + es1];
  const float* er0 = R_U + (size_t)(bg + es0) * (HH * 3);
  const float* er1 = R_U + (size_t)(bg + es1) * (HH * 3);

  unsigned short* Pbh = pool + wid * SLICE;   // fp16 [32 h][PbStr]: col = s*12+z*3+m
  unsigned short* Gbu = pool + wid * SLICE;   // bf16 [16 c][GbStr]  (aliases Pbh)

  // fwd-store ids (c<12)
  const int fs = (c * 86) >> 8, fm = c - 3 * fs;

  auto elem = [&](const float acc[12], float aa, float bb,
                  const float* rp, float g[12]) {
    float P0=acc[0],P1=acc[1],P2=acc[2];
    float V0=acc[3],V1=acc[4],V2=acc[5];
    float A0=acc[6],A1=acc[7],A2=acc[8];
    float J0=acc[9],J1=acc[10],J2=acc[11];
    float v2 = V0*V0 + V1*V1 + V2*V2;
    float v  = __builtin_amdgcn_sqrtf(v2);
    float ve = v + EPSF;
    float cx0 = V1*A2 - V2*A1;
    float cx1 = V2*A0 - V0*A2;
    float cx2 = V0*A1 - V1*A0;
    float nc  = __builtin_amdgcn_sqrtf(cx0*cx0 + cx1*cx1 + cx2*cx2);
    float ve2 = ve*ve;
    float denom = ve2*ve + EPSF;
    float invd  = __builtin_amdgcn_rcpf(denom);
    float kappa = nc * invd;
    float ks  = fminf(fmaxf(kappa, 1e-4f), 1e4f);
    float lpr = bb * __logf(ks);
    float lp  = fminf(fmaxf(lpr, -10.f), 10.f);
    float tr  = aa * __expf(lp);
    float tt  = fminf(fmaxf(tr, 1e-6f), 1e6f);
    float s2  = 2.f*l2*(v - tt);
    float gtr  = (tr > 1e-6f && tr < 1e6f) ? -s2 : 0.f;
    float glpr = (lpr > -10.f && lpr < 10.f) ? gtr*tr : 0.f;
    float gk   = (kappa > 1e-4f && kappa < 1e4f)
                   ? glpr*bb*__builtin_amdgcn_rcpf(ks) : 0.f;
    float gnc  = gk * invd;
    float gden = -gk * kappa * invd;
    float gve  = 3.f * ve2 * gden;
    float gv   = s2 + gve;
    float giv  = gv * __builtin_amdgcn_rcpf(v);
    float gcs  = gnc * __builtin_amdgcn_rcpf(nc);
    float gc0 = gcs*cx0, gc1 = gcs*cx1, gc2 = gcs*cx2;
    g[0]  = 2.f*l1*(P0 - rp[0]);
    g[1]  = 2.f*l1*(P1 - rp[1]);
    g[2]  = 2.f*l1*(P2 - rp[2]);
    g[3]  = fmaf(giv, V0, A1*gc2 - A2*gc1);
    g[4]  = fmaf(giv, V1, A2*gc0 - A0*gc2);
    g[5]  = fmaf(giv, V2, A0*gc1 - A1*gc0);
    g[6]  = gc1*V2 - gc2*V1;
    g[7]  = gc2*V0 - gc0*V2;
    g[8]  = gc0*V1 - gc1*V0;
    g[9]  = 2.f*l3*J0;
    g[10] = 2.f*l3*J1;
    g[11] = 2.f*l3*J2;
  };

  for (int it = 0; it < 3; ++it) {
    f32x4 gacc[4];
    #pragma unroll
    for (int mt = 0; mt < 4; ++mt) gacc[mt] = (f32x4){0.f, 0.f, 0.f, 0.f};

    // fwd B-frags (C fp16) for this iteration
    f16x8 cf0 = *(const f16x8*)&Cbf[lane * 8];
    f16x8 cf1 = *(const f16x8*)&Cbf[512 + lane * 8];

    for (int q = 0; q < 4; ++q) {
      // ---- forward: 8 MFMA-tiles (2 ht x 4 z), wave-local ----
      #pragma unroll
      for (int ht = 0; ht < 2; ++ht) {
        const int htg = wid * 8 + q * 2 + ht;
        #pragma unroll
        for (int z = 0; z < 4; ++z) {
          const unsigned short* pA =
              AFf + (size_t)((z * 32 + htg) * 2) * 512 + lane * 8;
          f16x8 af0 = *(const f16x8*)pA;
          f16x8 af1 = *(const f16x8*)(pA + 512);
          f32x4 d = {0.f, 0.f, 0.f, 0.f};
          d = __builtin_amdgcn_mfma_f32_16x16x32_f16(af0, cf0, d, 0, 0, 0);
          d = __builtin_amdgcn_mfma_f32_16x16x32_f16(af1, cf1, d, 0, 0, 0);
          if (c < 12) {
            unsigned short* pp =
                Pbh + (ht * 16 + quad * 4) * PbStr + fs * 12 + z * 3 + fm;
            pp[0 * PbStr] = f2h(d[0]);
            pp[1 * PbStr] = f2h(d[1]);
            pp[2 * PbStr] = f2h(d[2]);
            pp[3 * PbStr] = f2h(d[3]);
          }
        }
      }

      // ---- elementwise: this wave's 32 h, thread = (h, sample-pair) ----
      {
        // load ALL P values before any Gb store (Gb aliases Pb!)
        const unsigned short* p0 = Pbh + hq * PbStr + es0 * 12;
        const unsigned short* p1 = Pbh + hq * PbStr + es1 * 12;
        f16x4 a0 = *(const f16x4*)(p0);
        f16x4 a1 = *(const f16x4*)(p0 + 4);
        f16x4 a2 = *(const f16x4*)(p0 + 8);
        f16x4 b0v = *(const f16x4*)(p1);
        f16x4 b1v = *(const f16x4*)(p1 + 4);
        f16x4 b2v = *(const f16x4*)(p1 + 8);
        float acc0[12], acc1[12];
        #pragma unroll
        for (int j = 0; j < 4; ++j) {
          acc0[j]     = (float)a0[j];  acc1[j]     = (float)b0v[j];
          acc0[4 + j] = (float)a1[j];  acc1[4 + j] = (float)b1v[j];
          acc0[8 + j] = (float)a2[j];  acc1[8 + j] = (float)b2v[j];
        }
        const int hg = wid * 128 + q * 32 + hq;
        float g0[12], g1[12];
        elem(acc0, ea0, eb0, er0 + (size_t)hg * 3, g0);
        elem(acc1, ea1, eb1, er1 + (size_t)hg * 3, g1);
        #pragma unroll
        for (int z = 0; z < 4; ++z)
          #pragma unroll
          for (int m = 0; m < 3; ++m) {
            unsigned int pk = pkbf2(g0[z*3 + m], g1[z*3 + m]);
            Gbu[(3*es0 + m) * GbStr + z*32 + hq] = (unsigned short)pk;
            Gbu[(3*es1 + m) * GbStr + z*32 + hq] = (unsigned short)(pk >> 16);
          }
      }

      // ---- backward partial: all 4 m-tiles over this wave's K-slice ----
      #pragma unroll
      for (int ks2 = 0; ks2 < 4; ++ks2) {
        bf16x8 gg = *(const bf16x8*)&Gbu[c * GbStr + ks2 * 32 + quad * 8];
        #pragma unroll
        for (int mt = 0; mt < 4; ++mt) {
          const unsigned short* pA =
              AFb + (size_t)(((wid * 4 + q) * 4 + ks2) * 4 + mt) * 512 + lane * 8;
          bf16x8 a = *(const bf16x8*)pA;
          gacc[mt] = __builtin_amdgcn_mfma_f32_16x16x32_bf16(a, gg, gacc[mt], 0, 0, 0);
        }
      }
    }

    // ---- dump partials into OWN slice, reduce, update C ----
    {
      float* dmp = (float*)pool + wid * (SLICE / 2);
      #pragma unroll
      for (int mt = 0; mt < 4; ++mt)
        *(f32x4*)(dmp + mt * 256 + lane * 4) = gacc[mt];
    }
    __syncthreads();
    {
      const float* poolF = (const float*)pool;
      f32x4 tot = {0.f, 0.f, 0.f, 0.f};
      #pragma unroll
      for (int v = 0; v < 4; ++v)
        tot += *(const f32x4*)(poolF + v * (SLICE / 2) + wid * 256 + lane * 4);
      if (c < 12) {
        const int s = (c * 86) >> 8, m = c - 3 * s;
        const int kr = wid * 16 + quad * 4;
        #pragma unroll
        for (int r = 0; r < 4; ++r) {
          int k = kr + r;
          float val = Cl[s][k][m] - LR * tot[r];
          Cl[s][k][m] = val;
          Cbf[(k >> 5) * 512 + (((k >> 3) & 3) * 16 + c) * 8 + (k & 7)] = f2h(val);
        }
      }
    }
    __syncthreads();
  }

  const int ps = wid, psg = bg + ps;
  float* op = out + ((size_t)psg * KK + lane) * 3;
  op[0] = Cl[ps][lane][0];
  op[1] = Cl[ps][lane][1];
  op[2] = Cl[ps][lane][2];
}

extern "C" void kernel_launch(void* const* d_in, const int* in_sizes, int n_in,
                              void* d_out, int out_size, void* d_ws, size_t ws_size,
                              hipStream_t stream) {
  const float* R_U     = (const float*)d_in[0];
  const float* alpha   = (const float*)d_in[1];
  const float* beta    = (const float*)d_in[2];
  const float* lambdas = (const float*)d_in[3];
  const float* B       = (const float*)d_in[4];
  const float* Bd      = (const float*)d_in[5];
  const float* Bdd     = (const float*)d_in[6];
  const float* Bddd    = (const float*)d_in[7];
  const float* Bp      = (const float*)d_in[8];
  unsigned short* ws = (unsigned short*)d_ws;
  const int nB = in_sizes[1];   // 16384

  hipLaunchKernelGGL(prep_kernel, dim3(640), dim3(256), 0, stream,
                     B, Bd, Bdd, Bddd, Bp, ws);
  hipLaunchKernelGGL(copt_kernel, dim3(nB / SS), dim3(256), 0, stream,
                     R_U, alpha, beta, lambdas, ws, (float*)d_out);
}

// Round 6
// 407.737 us; speedup vs baseline: 1.8161x; 1.8161x over previous
//
#include <hip/hip_runtime.h>
#include <hip/hip_bf16.h>
#include <math.h>

#define EPSF 1e-8f
#define LR   1e-3f

#define HH 512
#define KK 64
#define SS 4          // samples per block
#define PbStr 56      // Pb row stride (ush): 48 data + 8 pad
#define GbStr 136     // Gb col stride (ush): 128 K + 8 pad
#define SLICE 2176    // per-wave slice (ush) = 4352 B

typedef short    bf16x8 __attribute__((ext_vector_type(8)));
typedef _Float16 f16x8  __attribute__((ext_vector_type(8)));
typedef _Float16 f16x4  __attribute__((ext_vector_type(4)));
typedef float    f32x4  __attribute__((ext_vector_type(4)));

__device__ __forceinline__ unsigned short f2bf(float x) {
  unsigned int u = __float_as_uint(x);
  return (unsigned short)((u + 0x7fffu + ((u >> 16) & 1u)) >> 16);
}
__device__ __forceinline__ float bfhi(float x) {
  return __uint_as_float(((unsigned int)f2bf(x)) << 16);
}
__device__ __forceinline__ unsigned short f2h(float x) {
  _Float16 h = (_Float16)x;
  return *(unsigned short*)&h;
}
__device__ __forceinline__ unsigned int pkbf2(float a, float b) {
  union { __hip_bfloat162 h; unsigned int u; } cv;
  cv.h = __float22bfloat162_rn(make_float2(a, b));
  return cv.u;
}

// elementwise gradient, all-scalar (no arrays -> guaranteed SROA)
__device__ __forceinline__ void elemf(
    float P0, float P1, float P2, float V0, float V1, float V2,
    float A0, float A1, float A2, float J0, float J1, float J2,
    float aa, float bb, float r0, float r1, float r2,
    float l1, float l2, float l3,
    float& o0, float& o1, float& o2, float& o3, float& o4, float& o5,
    float& o6, float& o7, float& o8, float& o9, float& o10, float& o11) {
  float v2 = V0*V0 + V1*V1 + V2*V2;
  float v  = __builtin_amdgcn_sqrtf(v2);
  float ve = v + EPSF;
  float cx0 = V1*A2 - V2*A1;
  float cx1 = V2*A0 - V0*A2;
  float cx2 = V0*A1 - V1*A0;
  float nc  = __builtin_amdgcn_sqrtf(cx0*cx0 + cx1*cx1 + cx2*cx2);
  float ve2 = ve*ve;
  float denom = ve2*ve + EPSF;
  float invd  = __builtin_amdgcn_rcpf(denom);
  float kappa = nc * invd;
  float ks  = fminf(fmaxf(kappa, 1e-4f), 1e4f);
  float lpr = bb * __logf(ks);
  float lp  = fminf(fmaxf(lpr, -10.f), 10.f);
  float tr  = aa * __expf(lp);
  float tt  = fminf(fmaxf(tr, 1e-6f), 1e6f);
  float s2  = 2.f*l2*(v - tt);
  float gtr  = (tr > 1e-6f && tr < 1e6f) ? -s2 : 0.f;
  float glpr = (lpr > -10.f && lpr < 10.f) ? gtr*tr : 0.f;
  float gk   = (kappa > 1e-4f && kappa < 1e4f)
                 ? glpr*bb*__builtin_amdgcn_rcpf(ks) : 0.f;
  float gnc  = gk * invd;
  float gden = -gk * kappa * invd;
  float gve  = 3.f * ve2 * gden;
  float gv   = s2 + gve;
  float giv  = gv * __builtin_amdgcn_rcpf(v);
  float gcs  = gnc * __builtin_amdgcn_rcpf(nc);
  float gc0 = gcs*cx0, gc1 = gcs*cx1, gc2 = gcs*cx2;
  o0  = 2.f*l1*(P0 - r0);
  o1  = 2.f*l1*(P1 - r1);
  o2  = 2.f*l1*(P2 - r2);
  o3  = fmaf(giv, V0, A1*gc2 - A2*gc1);
  o4  = fmaf(giv, V1, A2*gc0 - A0*gc2);
  o5  = fmaf(giv, V2, A0*gc1 - A1*gc0);
  o6  = gc1*V2 - gc2*V1;
  o7  = gc2*V0 - gc0*V2;
  o8  = gc0*V1 - gc1*V0;
  o9  = 2.f*l3*J0;
  o10 = 2.f*l3*J1;
  o11 = 2.f*l3*J2;
}

// ws layout (ushort units):
//  AFb @ 0      (131072): bwd A-frags, single bf16
//     f = ((chunk*4+qtr)*4+ks2)*4+mt; elem = f*512 + lane*8 + j
//     khat=mt*16+(lane&15); kq=(lane>>4)*8+j; h=chunk*128+qtr*32+kq; val=Ms[ks2][h*64+khat]
//  AFf @ 131072 (131072): fwd A-frags fp16
//     f=(z*32+ht)*2+kap; elem=f*512+lane*8+j
//     h=ht*16+(lane&15); kk=kap*32+(lane>>4)*8+j; val=Ms[z][h*64+kk]
//  AFp @ 262144 (65536): C0 A-frags bf16 hi/lo (Bp)
//     f=(ks*4+mt)*2+hilo; elem=f*512+lane*8+j
//     khat=mt*16+(lane&15); Kl=ks*32+(lane>>4)*8+j; val=Bp[khat*512+Kl]
__global__ void prep_kernel(const float* __restrict__ B,
                            const float* __restrict__ Bd,
                            const float* __restrict__ Bdd,
                            const float* __restrict__ Bddd,
                            const float* __restrict__ Bp,
                            unsigned short* __restrict__ ws) {
  int tid = blockIdx.x * 256 + threadIdx.x;   // 640 * 256 = 163840
  const float* Ms[4] = {B, Bd, Bdd, Bddd};
  unsigned short bits[2];
  if (tid < 65536) {
    #pragma unroll
    for (int t = 0; t < 2; ++t) {
      unsigned int id = 2u * tid + t;
      int j = id & 7, lane = (id >> 3) & 63;
      int mt = (id >> 9) & 3, ks2 = (id >> 11) & 3;
      int qtr = (id >> 13) & 3, chunk = (id >> 15) & 3;
      int khat = mt * 16 + (lane & 15);
      int kq = ((lane >> 4) << 3) + j;
      int h = chunk * 128 + qtr * 32 + kq;
      bits[t] = f2bf(Ms[ks2][h * 64 + khat]);
    }
    ((unsigned int*)ws)[tid] = ((unsigned int)bits[1] << 16) | bits[0];
  } else if (tid < 131072) {
    int base = tid - 65536;
    #pragma unroll
    for (int t = 0; t < 2; ++t) {
      unsigned int id = 2u * base + t;
      int j = id & 7, lane = (id >> 3) & 63, kap = (id >> 9) & 1;
      int ht = (id >> 10) & 31, z = (id >> 15) & 3;
      int h = ht * 16 + (lane & 15);
      int kk = kap * 32 + ((lane >> 4) << 3) + j;
      bits[t] = f2h(Ms[z][h * 64 + kk]);
    }
    ((unsigned int*)(ws + 131072))[base] = ((unsigned int)bits[1] << 16) | bits[0];
  } else {
    int base = tid - 131072;
    #pragma unroll
    for (int t = 0; t < 2; ++t) {
      unsigned int id = 2u * base + t;
      int j = id & 7, lane = (id >> 3) & 63, hilo = (id >> 9) & 1;
      int mt = (id >> 10) & 3, ks = (id >> 12) & 15;
      int khat = mt * 16 + (lane & 15);
      int Kl = ks * 32 + ((lane >> 4) << 3) + j;
      float val = Bp[khat * 512 + Kl];
      float hi = bfhi(val);
      bits[t] = hilo ? f2bf(val - hi) : f2bf(hi);
    }
    ((unsigned int*)(ws + 262144))[base] = ((unsigned int)bits[1] << 16) | bits[0];
  }
}

__global__ __launch_bounds__(256, 4)
void copt_kernel(const float* __restrict__ R_U,
                 const float* __restrict__ alpha,
                 const float* __restrict__ beta,
                 const float* __restrict__ lambdas,
                 const unsigned short* __restrict__ ws,
                 float* __restrict__ out) {
  __shared__ __align__(16) float Cl[SS][KK][3];            // 3 KB fp32 C
  __shared__ __align__(16) unsigned short Cbf[2 * 512];    // 2 KB fp16 C B-frags
  __shared__ __align__(16) unsigned short pool[4 * SLICE]; // 17 KB per-wave Pb/Gb (aliased) + dump

  const unsigned short* AFb = ws;
  const unsigned short* AFf = ws + 131072;
  const unsigned short* AFp = ws + 262144;

  const int tid  = threadIdx.x;
  const int lane = tid & 63;
  const int wid  = tid >> 6;
  const int quad = lane >> 4;
  const int c    = lane & 15;

  const float l1 = lambdas[0], l2 = lambdas[1], l3 = lambdas[2];
  const int bg = blockIdx.x * SS;

  if (tid < 512) ((unsigned int*)Cbf)[tid] = 0u;   // cols 12..15 stay 0 forever

  // ---- stage r -> pool (bf16): [col=3s+m][h], stride 520 (s=wid) ----
  {
    const int s = wid, sg = bg + s;
    const float4* rp = (const float4*)(R_U + (size_t)sg * (HH * 3));
    #pragma unroll
    for (int i = 0; i < 6; ++i) {
      float4 v = rp[i * 64 + lane];
      int e = (i * 64 + lane) * 4;
      const float* pv = &v.x;
      #pragma unroll
      for (int d = 0; d < 4; ++d) {
        int ee = e + d, h = ee / 3, m = ee - 3 * h;
        pool[(3 * s + m) * 520 + h] = f2bf(pv[d]);
      }
    }
  }
  __syncthreads();

  // ---- C0 = Bp @ r via MFMA (bf16 hi/lo A, bf16 r); this wave: mt = wid ----
  {
    f32x4 cacc = {0.f, 0.f, 0.f, 0.f};
    const unsigned short* gb = &pool[c * 520 + quad * 8];
    #pragma unroll 4
    for (int ks = 0; ks < 16; ++ks) {
      const unsigned short* pA = AFp + (size_t)((ks * 4 + wid) * 2) * 512 + lane * 8;
      bf16x8 ah = *(const bf16x8*)pA;
      bf16x8 al = *(const bf16x8*)(pA + 512);
      bf16x8 gg = *(const bf16x8*)(gb + ks * 32);
      cacc = __builtin_amdgcn_mfma_f32_16x16x32_bf16(ah, gg, cacc, 0, 0, 0);
      cacc = __builtin_amdgcn_mfma_f32_16x16x32_bf16(al, gg, cacc, 0, 0, 0);
    }
    if (c < 12) {
      const int s = (c * 86) >> 8, m = c - 3 * s;
      const int kr = wid * 16 + quad * 4;
      #pragma unroll
      for (int r = 0; r < 4; ++r) {
        float val = cacc[r];
        int k = kr + r;
        Cl[s][k][m] = val;
        Cbf[(k >> 5) * 512 + (((k >> 3) & 3) * 16 + c) * 8 + (k & 7)] = f2h(val);
      }
    }
  }
  __syncthreads();

  // elem thread ids: h = hq (lane&31), sample-pair by lane>>5
  const int hq = lane & 31;
  const int es0 = 2 * (lane >> 5), es1 = es0 + 1;
  const float ea0 = alpha[bg + es0], ea1 = alpha[bg + es1];
  const float eb0 = beta[bg + es0],  eb1 = beta[bg + es1];
  const float* er0 = R_U + (size_t)(bg + es0) * (HH * 3);
  const float* er1 = R_U + (size_t)(bg + es1) * (HH * 3);

  unsigned short* Pbh = pool + wid * SLICE;   // fp16 [32 h][PbStr]: col = s*12+z*3+m
  unsigned short* Gbu = pool + wid * SLICE;   // bf16 [16 c][GbStr]  (aliases Pbh)

  // fwd-store ids (c<12)
  const int fs = (c * 86) >> 8, fm = c - 3 * fs;

  for (int it = 0; it < 3; ++it) {
    f32x4 gacc0 = {0.f,0.f,0.f,0.f}, gacc1 = {0.f,0.f,0.f,0.f};
    f32x4 gacc2 = {0.f,0.f,0.f,0.f}, gacc3 = {0.f,0.f,0.f,0.f};

    // fwd B-frags (C fp16) for this iteration
    f16x8 cf0 = *(const f16x8*)&Cbf[lane * 8];
    f16x8 cf1 = *(const f16x8*)&Cbf[512 + lane * 8];

    for (int q = 0; q < 4; ++q) {
      // ---- forward: 8 MFMA-tiles (2 ht x 4 z), wave-local ----
      #pragma unroll
      for (int ht = 0; ht < 2; ++ht) {
        const int htg = wid * 8 + q * 2 + ht;
        #pragma unroll
        for (int z = 0; z < 4; ++z) {
          const unsigned short* pA =
              AFf + (size_t)((z * 32 + htg) * 2) * 512 + lane * 8;
          f16x8 af0 = *(const f16x8*)pA;
          f16x8 af1 = *(const f16x8*)(pA + 512);
          f32x4 d = {0.f, 0.f, 0.f, 0.f};
          d = __builtin_amdgcn_mfma_f32_16x16x32_f16(af0, cf0, d, 0, 0, 0);
          d = __builtin_amdgcn_mfma_f32_16x16x32_f16(af1, cf1, d, 0, 0, 0);
          if (c < 12) {
            unsigned short* pp =
                Pbh + (ht * 16 + quad * 4) * PbStr + fs * 12 + z * 3 + fm;
            pp[0 * PbStr] = f2h(d[0]);
            pp[1 * PbStr] = f2h(d[1]);
            pp[2 * PbStr] = f2h(d[2]);
            pp[3 * PbStr] = f2h(d[3]);
          }
        }
      }

      // ---- elementwise: this wave's 32 h, thread = (h, sample-pair) ----
      {
        // load ALL P values before any Gb store (Gb aliases Pb!)
        const unsigned short* p0 = Pbh + hq * PbStr + es0 * 12;
        const unsigned short* p1 = Pbh + hq * PbStr + es1 * 12;
        f16x4 va0 = *(const f16x4*)(p0);
        f16x4 va1 = *(const f16x4*)(p0 + 4);
        f16x4 va2 = *(const f16x4*)(p0 + 8);
        f16x4 vb0 = *(const f16x4*)(p1);
        f16x4 vb1 = *(const f16x4*)(p1 + 4);
        f16x4 vb2 = *(const f16x4*)(p1 + 8);
        const int hg = wid * 128 + q * 32 + hq;
        float r00 = er0[(size_t)hg*3], r01 = er0[(size_t)hg*3+1], r02 = er0[(size_t)hg*3+2];
        float r10 = er1[(size_t)hg*3], r11 = er1[(size_t)hg*3+1], r12 = er1[(size_t)hg*3+2];

        float gA0,gA1,gA2,gA3,gA4,gA5,gA6,gA7,gA8,gA9,gA10,gA11;
        float gB0,gB1,gB2,gB3,gB4,gB5,gB6,gB7,gB8,gB9,gB10,gB11;
        elemf((float)va0[0],(float)va0[1],(float)va0[2],(float)va0[3],
              (float)va1[0],(float)va1[1],(float)va1[2],(float)va1[3],
              (float)va2[0],(float)va2[1],(float)va2[2],(float)va2[3],
              ea0, eb0, r00, r01, r02, l1, l2, l3,
              gA0,gA1,gA2,gA3,gA4,gA5,gA6,gA7,gA8,gA9,gA10,gA11);
        elemf((float)vb0[0],(float)vb0[1],(float)vb0[2],(float)vb0[3],
              (float)vb1[0],(float)vb1[1],(float)vb1[2],(float)vb1[3],
              (float)vb2[0],(float)vb2[1],(float)vb2[2],(float)vb2[3],
              ea1, eb1, r10, r11, r12, l1, l2, l3,
              gB0,gB1,gB2,gB3,gB4,gB5,gB6,gB7,gB8,gB9,gB10,gB11);

        #define STOREG(zz, mm, GA, GB) { \
          unsigned int pk = pkbf2(GA, GB); \
          Gbu[(3*es0 + mm) * GbStr + (zz)*32 + hq] = (unsigned short)pk; \
          Gbu[(3*es1 + mm) * GbStr + (zz)*32 + hq] = (unsigned short)(pk >> 16); }
        STOREG(0, 0, gA0, gB0)  STOREG(0, 1, gA1, gB1)  STOREG(0, 2, gA2, gB2)
        STOREG(1, 0, gA3, gB3)  STOREG(1, 1, gA4, gB4)  STOREG(1, 2, gA5, gB5)
        STOREG(2, 0, gA6, gB6)  STOREG(2, 1, gA7, gB7)  STOREG(2, 2, gA8, gB8)
        STOREG(3, 0, gA9, gB9)  STOREG(3, 1, gA10, gB10) STOREG(3, 2, gA11, gB11)
        #undef STOREG
      }

      // ---- backward partial: all 4 m-tiles over this wave's K-slice ----
      #pragma unroll
      for (int ks2 = 0; ks2 < 4; ++ks2) {
        bf16x8 gg = *(const bf16x8*)&Gbu[c * GbStr + ks2 * 32 + quad * 8];
        const unsigned short* pA0 =
            AFb + (size_t)(((wid * 4 + q) * 4 + ks2) * 4) * 512 + lane * 8;
        bf16x8 a0 = *(const bf16x8*)(pA0);
        bf16x8 a1 = *(const bf16x8*)(pA0 + 512);
        bf16x8 a2 = *(const bf16x8*)(pA0 + 1024);
        bf16x8 a3 = *(const bf16x8*)(pA0 + 1536);
        gacc0 = __builtin_amdgcn_mfma_f32_16x16x32_bf16(a0, gg, gacc0, 0, 0, 0);
        gacc1 = __builtin_amdgcn_mfma_f32_16x16x32_bf16(a1, gg, gacc1, 0, 0, 0);
        gacc2 = __builtin_amdgcn_mfma_f32_16x16x32_bf16(a2, gg, gacc2, 0, 0, 0);
        gacc3 = __builtin_amdgcn_mfma_f32_16x16x32_bf16(a3, gg, gacc3, 0, 0, 0);
      }
    }

    // ---- dump partials into OWN slice, reduce, update C ----
    {
      float* dmp = (float*)pool + wid * (SLICE / 2);
      *(f32x4*)(dmp +   0 + lane * 4) = gacc0;
      *(f32x4*)(dmp + 256 + lane * 4) = gacc1;
      *(f32x4*)(dmp + 512 + lane * 4) = gacc2;
      *(f32x4*)(dmp + 768 + lane * 4) = gacc3;
    }
    __syncthreads();
    {
      const float* poolF = (const float*)pool;
      f32x4 tot = {0.f, 0.f, 0.f, 0.f};
      #pragma unroll
      for (int v = 0; v < 4; ++v)
        tot += *(const f32x4*)(poolF + v * (SLICE / 2) + wid * 256 + lane * 4);
      if (c < 12) {
        const int s = (c * 86) >> 8, m = c - 3 * s;
        const int kr = wid * 16 + quad * 4;
        #pragma unroll
        for (int r = 0; r < 4; ++r) {
          int k = kr + r;
          float val = Cl[s][k][m] - LR * tot[r];
          Cl[s][k][m] = val;
          Cbf[(k >> 5) * 512 + (((k >> 3) & 3) * 16 + c) * 8 + (k & 7)] = f2h(val);
        }
      }
    }
    __syncthreads();
  }

  const int ps = wid, psg = bg + ps;
  float* op = out + ((size_t)psg * KK + lane) * 3;
  op[0] = Cl[ps][lane][0];
  op[1] = Cl[ps][lane][1];
  op[2] = Cl[ps][lane][2];
}

extern "C" void kernel_launch(void* const* d_in, const int* in_sizes, int n_in,
                              void* d_out, int out_size, void* d_ws, size_t ws_size,
                              hipStream_t stream) {
  const float* R_U     = (const float*)d_in[0];
  const float* alpha   = (const float*)d_in[1];
  const float* beta    = (const float*)d_in[2];
  const float* lambdas = (const float*)d_in[3];
  const float* B       = (const float*)d_in[4];
  const float* Bd      = (const float*)d_in[5];
  const float* Bdd     = (const float*)d_in[6];
  const float* Bddd    = (const float*)d_in[7];
  const float* Bp      = (const float*)d_in[8];
  unsigned short* ws = (unsigned short*)d_ws;
  const int nB = in_sizes[1];   // 16384

  hipLaunchKernelGGL(prep_kernel, dim3(640), dim3(256), 0, stream,
                     B, Bd, Bdd, Bddd, Bp, ws);
  hipLaunchKernelGGL(copt_kernel, dim3(nB / SS), dim3(256), 0, stream,
                     R_U, alpha, beta, lambdas, ws, (float*)d_out);
}